// Round 2
// baseline (2409.364 us; speedup 1.0000x reference)
//
#include <hip/hip_runtime.h>
#include <hip/hip_bf16.h>

// Problem constants
#define NB   256           // batch
#define NC   64            // in channels
#define NO   64            // out channels
#define NN   23            // nodes
#define NL   35            // seq len
#define NH   3             // heads
#define NNL  805           // NN*NL
#define CNL  51520         // NC*NNL (per-batch x elements)
#define NSQ  529           // NN*NN
#define HF   1587          // NH*NSQ

// ws layout (float offsets). Total ~828,544 floats = 3.31 MB.
#define OFF_W     0         // [3][64][64]  = 12288
#define OFF_U1    12288     // [3][64]
#define OFF_U2    12480     // [3][64]
#define OFF_S     12672     // [3] (pad to 12800)
#define OFF_ATTM  12800     // [256][1587] = 406272 -> ends 419072
#define OFF_MEAN  419072    // [1587] -> pad to 420672
#define OFF_RSTD  420672    // [1587] -> pad to 422272
#define OFF_A     422272    // [256][1587] = 406272 -> ends 828544

// ---------------------------------------------------------------------------
// Kernel 1: fold projection weights.
// W[h][c2][c1] = sum_o cw2[h,o,c2]*cw1[h,o,c1]
// u1[h][c1]   = sum_o cb2[h,o]*cw1[h,o,c1]
// u2[h][c2]   = sum_o cb1[h,o]*cw2[h,o,c2]
// s[h]        = sum_o cb1[h,o]*cb2[h,o]
__global__ __launch_bounds__(256) void k_prep(const float* __restrict__ cw1,
                                              const float* __restrict__ cb1,
                                              const float* __restrict__ cw2,
                                              const float* __restrict__ cb2,
                                              float* __restrict__ ws) {
    int h = blockIdx.x, t = threadIdx.x;
    __shared__ float s1[4096], s2[4096];
    for (int i = t; i < 4096; i += 256) {
        s1[i] = cw1[h * 4096 + i];
        s2[i] = cw2[h * 4096 + i];
    }
    __syncthreads();
    for (int i = t; i < 4096; i += 256) {
        int c2 = i >> 6, c1 = i & 63;
        float acc = 0.f;
        for (int o = 0; o < 64; o++) acc += s2[o * 64 + c2] * s1[o * 64 + c1];
        ws[OFF_W + h * 4096 + i] = acc;
    }
    if (t < 64) {
        float a = 0.f, b2 = 0.f;
        for (int o = 0; o < 64; o++) {
            a  += cb2[h * 64 + o] * s1[o * 64 + t];
            b2 += cb1[h * 64 + o] * s2[o * 64 + t];
        }
        ws[OFF_U1 + h * 64 + t] = a;
        ws[OFF_U2 + h * 64 + t] = b2;
    }
    if (t == 0) {
        float a = 0.f;
        for (int o = 0; o < 64; o++)
            a += cb1[h * 64 + o] * cb2[h * 64 + o];
        ws[OFF_S + h] = a;
    }
}

// ---------------------------------------------------------------------------
// Kernel 2: att_m[b,h,m,n] = (sum_l X_l^T W X_l + a1[n] + a2[m] + 35*s)/2240
// One block per (b,h). X_l is [c=64][n=23] slice of x[b,:, :, l].
__global__ __launch_bounds__(256) void k_attm(const float* __restrict__ x,
                                              float* __restrict__ ws) {
    int b = blockIdx.x, h = blockIdx.y, t = threadIdx.x;
    __shared__ float sW[64 * 65];   // W padded rows (65 % 32 == 1 -> conflict-free)
    __shared__ float sX[64 * 24];   // X_l[c][n], pad to 24
    __shared__ float sP[64 * 24];   // P = W @ X_l (also holds per-n l-sums early)
    __shared__ float sQ[23 * 24];   // attq accumulator [m][n]
    __shared__ float sA1[23], sA2[23];

    const float* xb = x + b * CNL;  // strides: c:805, n:35, l:1
    const float* Wg = ws + OFF_W + h * 4096;
    for (int i = t; i < 4096; i += 256) sW[(i >> 6) * 65 + (i & 63)] = Wg[i];
    for (int i = t; i < 552; i += 256) sQ[i] = 0.f;

    // xs[c][n] = sum_l x[c][n][l]  (into sP, consumed before main loop)
    for (int i = t; i < 1472; i += 256) {
        int c = i / 23, n = i - c * 23;
        const float* p = xb + c * NNL + n * NL;
        float s = 0.f;
        for (int l = 0; l < NL; l++) s += p[l];
        sP[c * 24 + n] = s;
    }
    __syncthreads();
    if (t < 23) {
        float a = 0.f;
        const float* u = ws + OFF_U1 + h * 64;
        for (int c = 0; c < 64; c++) a += u[c] * sP[c * 24 + t];
        sA1[t] = a;
    } else if (t >= 32 && t < 55) {
        int n = t - 32;
        float a = 0.f;
        const float* u = ws + OFF_U2 + h * 64;
        for (int c = 0; c < 64; c++) a += u[c] * sP[c * 24 + n];
        sA2[n] = a;
    }

    int c2 = t & 63;          // wave-uniform q = t>>6 -> X reads broadcast per wave
    int q  = t >> 6;
    int n0 = q * 6;
    int nv = (q == 3) ? 5 : 6;

    for (int l = 0; l < NL; l++) {
        __syncthreads();  // prev iteration readers done before overwriting sX/sP
        for (int i = t; i < 1472; i += 256) {
            int c = i / 23, n = i - c * 23;
            sX[c * 24 + n] = xb[c * NNL + n * NL + l];
        }
        if (t < 64) sX[t * 24 + 23] = 0.f;   // zero pad column (read by q==3 lane j=5)
        __syncthreads();
        // P[c2][n] = sum_c1 W[c2][c1] * X[c1][n], 6 n's per thread
        float a0 = 0, a1 = 0, a2 = 0, a3 = 0, a4 = 0, a5 = 0;
        for (int c1 = 0; c1 < 64; c1++) {
            float w = sW[c2 * 65 + c1];
            const float* xr = &sX[c1 * 24 + n0];
            a0 += w * xr[0]; a1 += w * xr[1]; a2 += w * xr[2];
            a3 += w * xr[3]; a4 += w * xr[4]; a5 += w * xr[5];
        }
        float accs[6] = {a0, a1, a2, a3, a4, a5};
        for (int j = 0; j < nv; j++) sP[c2 * 24 + n0 + j] = accs[j];
        __syncthreads();
        // attq[m][n] += sum_c2 X[c2][m] * P[c2][n]
        for (int i = t; i < 529; i += 256) {
            int m = i / 23, n = i - m * 23;
            float a = 0.f;
            for (int c = 0; c < 64; c++) a += sX[c * 24 + m] * sP[c * 24 + n];
            sQ[m * 24 + n] += a;
        }
    }
    __syncthreads();
    float sh = ws[OFF_S + h];
    float* o = ws + OFF_ATTM + b * HF + h * NSQ;
    for (int i = t; i < 529; i += 256) {
        int m = i / 23, n = i - m * 23;
        o[i] = (sQ[m * 24 + n] + sA1[n] + sA2[m] + 35.f * sh) * (1.f / 2240.f);
    }
}

// ---------------------------------------------------------------------------
// Kernel 3: BN batch statistics per (h, feature). Biased variance (torch BN).
__global__ __launch_bounds__(256) void k_bn(float* __restrict__ ws) {
    int f = blockIdx.x * 256 + threadIdx.x;
    if (f >= HF) return;
    const float* p = ws + OFF_ATTM + f;
    float s = 0.f, s2 = 0.f;
    for (int b = 0; b < NB; b++) {
        float v = p[b * HF];
        s += v; s2 += v * v;
    }
    float mean = s * (1.f / 256.f);
    float var  = s2 * (1.f / 256.f) - mean * mean;
    ws[OFF_MEAN + f] = mean;
    ws[OFF_RSTD + f] = rsqrtf(var + 1e-5f);
}

// ---------------------------------------------------------------------------
// Kernel 4: normalize, softmax over axis=-2 (row index m, per column n),
// then A = A_ske + att + A_adp. One block per (b,h).
__global__ __launch_bounds__(256) void k_adp(const float* __restrict__ gamma,
                                             const float* __restrict__ beta,
                                             const float* __restrict__ att,
                                             const float* __restrict__ aske,
                                             float* __restrict__ ws) {
    int b = blockIdx.x, h = blockIdx.y, t = threadIdx.x;
    __shared__ float sv[529];
    const float* am   = ws + OFF_ATTM + b * HF + h * NSQ;
    const float* mean = ws + OFF_MEAN + h * NSQ;
    const float* rstd = ws + OFF_RSTD + h * NSQ;
    for (int i = t; i < 529; i += 256) {
        sv[i] = (am[i] - mean[i]) * rstd[i] * gamma[h * NSQ + i] + beta[h * NSQ + i];
    }
    __syncthreads();
    if (t < 23) {   // column t; softmax over m (stride 23, odd -> conflict-free)
        float mx = -1e30f;
        #pragma unroll
        for (int m = 0; m < 23; m++) mx = fmaxf(mx, sv[m * 23 + t]);
        float e[23];
        float sum = 0.f;
        #pragma unroll
        for (int m = 0; m < 23; m++) {
            float v = __expf(sv[m * 23 + t] - mx);
            e[m] = v; sum += v;
        }
        float inv = 1.f / sum;
        #pragma unroll
        for (int m = 0; m < 23; m++) sv[m * 23 + t] = e[m] * inv;
    }
    __syncthreads();
    float* o = ws + OFF_A + b * HF + h * NSQ;
    for (int i = t; i < 529; i += 256) {
        o[i] = sv[i] + aske[h * NSQ + i] + att[h * NSQ + i];
    }
}

// ---------------------------------------------------------------------------
// Kernel 5: graph conv + temporal FC, fused per (o-tile of 16, b).
// y[o,m,l] = sum_h sum_n A_h[n,m] * (sum_c mw[h,o,c]*x[c,n,l]) + sum_h mb[h,o]
// out[b,o,m,mp] = sum_l y[o,m,l]*Wseq[l,mp] + bias[mp]
__global__ __launch_bounds__(576) void k_gcn(const float* __restrict__ x,
                                             const float* __restrict__ mw,
                                             const float* __restrict__ mb,
                                             const float* __restrict__ wseq,
                                             const float* __restrict__ bias,
                                             const float* __restrict__ ws,
                                             float* __restrict__ out) {
    int ot = blockIdx.x;          // o-tile 0..3
    int b  = blockIdx.y;
    int t  = threadIdx.x;
    int obase = ot * 16;
    __shared__ float sA[3 * 529];
    __shared__ float sMW[3][16][65];
    __shared__ float sWS[35][36];
    __shared__ float sY[16][23][36];
    __shared__ float sBias[35];
    __shared__ float sMB[16];

    const float* Ab = ws + OFF_A + b * HF;
    for (int i = t; i < HF; i += 576) sA[i] = Ab[i];
    for (int i = t; i < 3 * 16 * 64; i += 576) {
        int h = i >> 10, r = i & 1023;
        int o = r >> 6, c = r & 63;
        sMW[h][o][c] = mw[h * 4096 + (obase + o) * 64 + c];
    }
    for (int i = t; i < 35 * 35; i += 576) {
        int l = i / 35, m = i - l * 35;
        sWS[l][m] = wseq[i];
    }
    if (t < 35) sBias[t] = bias[t];
    if (t < 16) sMB[t] = mb[obase + t] + mb[64 + obase + t] + mb[128 + obase + t];
    __syncthreads();

    int o = t / 35, l = t - o * 35;   // valid for t < 560
    if (t < 560) {
        float yreg[23];
        float init = sMB[o];
        #pragma unroll
        for (int m = 0; m < 23; m++) yreg[m] = init;
        const float* xb = x + b * CNL + l;
        for (int n = 0; n < NN; n++) {
            float z0 = 0.f, z1 = 0.f, z2 = 0.f;
            const float* xp = xb + n * NL;
            for (int c = 0; c < 64; c++) {
                float xv = xp[c * NNL];
                z0 += sMW[0][o][c] * xv;
                z1 += sMW[1][o][c] * xv;
                z2 += sMW[2][o][c] * xv;
            }
            const float* A0 = &sA[n * 23];
            const float* A1 = &sA[529 + n * 23];
            const float* A2 = &sA[1058 + n * 23];
            #pragma unroll
            for (int m = 0; m < 23; m++)
                yreg[m] += A0[m] * z0 + A1[m] * z1 + A2[m] * z2;
        }
        #pragma unroll
        for (int m = 0; m < 23; m++) sY[o][m][l] = yreg[m];
    }
    __syncthreads();
    if (t < 560) {
        int lp = l;
        float* ob = out + b * CNL + (obase + o) * NNL + lp;
        for (int m = 0; m < NN; m++) {
            float acc = sBias[lp];
            const float* yr = sY[o][m];
            for (int l2 = 0; l2 < NL; l2++) acc += yr[l2] * sWS[l2][lp];
            ob[m * NL] = acc;
        }
    }
}

// ---------------------------------------------------------------------------
extern "C" void kernel_launch(void* const* d_in, const int* in_sizes, int n_in,
                              void* d_out, int out_size, void* d_ws, size_t ws_size,
                              hipStream_t stream) {
    const float* x    = (const float*)d_in[0];
    const float* cw1  = (const float*)d_in[1];
    const float* cb1  = (const float*)d_in[2];
    const float* cw2  = (const float*)d_in[3];
    const float* cb2  = (const float*)d_in[4];
    const float* gam  = (const float*)d_in[5];
    const float* bet  = (const float*)d_in[6];
    const float* mw   = (const float*)d_in[7];
    const float* mb   = (const float*)d_in[8];
    const float* att  = (const float*)d_in[9];
    const float* aske = (const float*)d_in[10];
    const float* wsq  = (const float*)d_in[11];
    const float* bias = (const float*)d_in[12];
    float* ws = (float*)d_ws;
    float* out = (float*)d_out;

    hipLaunchKernelGGL(k_prep, dim3(3),      dim3(256), 0, stream, cw1, cb1, cw2, cb2, ws);
    hipLaunchKernelGGL(k_attm, dim3(256, 3), dim3(256), 0, stream, x, ws);
    hipLaunchKernelGGL(k_bn,   dim3(7),      dim3(256), 0, stream, ws);
    hipLaunchKernelGGL(k_adp,  dim3(256, 3), dim3(256), 0, stream, gam, bet, att, aske, ws);
    hipLaunchKernelGGL(k_gcn,  dim3(4, 256), dim3(576), 0, stream, x, mw, mb, wsq, bias, ws, out);
}

// Round 3
// 2408.470 us; speedup vs baseline: 1.0004x; 1.0004x over previous
//
#include <hip/hip_runtime.h>
#include <hip/hip_bf16.h>

typedef __hip_bfloat16 bf16;

// Problem constants
#define NB   256           // batch
#define NN   23            // nodes
#define NL   35            // seq len
#define NNL  805           // NN*NL
#define CNL  51520         // NC*NNL (per-batch x elements)
#define NSQ  529           // NN*NN
#define HF   1587          // NH*NSQ

// ws layout (float offsets)
#define OFF_W     0         // [3][64][64]
#define OFF_U1    12288
#define OFF_U2    12480
#define OFF_S     12672
#define OFF_ATTM  12800     // [256][1587]
#define OFF_MEAN  419072
#define OFF_RSTD  420672
#define OFF_A     422272    // [256][1587] -> ends 828544
#define OFF_MWT   828544    // mw transposed [3][64c][64o] -> 840832
#define OFF_MBS   840832    // mbsum[64] -> 840896 (pad 840960)
#define OFF_Y     840960    // bf16 y-buffer: per pass [128][23][35][64] = 13.2 MB
// total ws ~= 16.6 MB

// ---------------------------------------------------------------------------
// Kernel 1: fold projection weights; block 3 transposes mw and sums mb.
__global__ __launch_bounds__(256) void k_prep(const float* __restrict__ cw1,
                                              const float* __restrict__ cb1,
                                              const float* __restrict__ cw2,
                                              const float* __restrict__ cb2,
                                              const float* __restrict__ mw,
                                              const float* __restrict__ mb,
                                              float* __restrict__ ws) {
    int h = blockIdx.x, t = threadIdx.x;
    __shared__ float s1[4096], s2[4096];
    if (h < 3) {
        for (int i = t; i < 4096; i += 256) {
            s1[i] = cw1[h * 4096 + i];
            s2[i] = cw2[h * 4096 + i];
        }
        __syncthreads();
        for (int i = t; i < 4096; i += 256) {
            int c2 = i >> 6, c1 = i & 63;
            float acc = 0.f;
            for (int o = 0; o < 64; o++) acc += s2[o * 64 + c2] * s1[o * 64 + c1];
            ws[OFF_W + h * 4096 + i] = acc;
        }
        if (t < 64) {
            float a = 0.f, b2 = 0.f;
            for (int o = 0; o < 64; o++) {
                a  += cb2[h * 64 + o] * s1[o * 64 + t];
                b2 += cb1[h * 64 + o] * s2[o * 64 + t];
            }
            ws[OFF_U1 + h * 64 + t] = a;
            ws[OFF_U2 + h * 64 + t] = b2;
        }
        if (t == 0) {
            float a = 0.f;
            for (int o = 0; o < 64; o++) a += cb1[h * 64 + o] * cb2[h * 64 + o];
            ws[OFF_S + h] = a;
        }
    } else {
        // mwT[h][c][o] = mw[h][o][c]
        for (int i = t; i < 12288; i += 256) {
            int hh = i >> 12, rem = i & 4095, o = rem >> 6, c = rem & 63;
            ws[OFF_MWT + (hh * 64 + c) * 64 + o] = mw[i];
        }
        if (t < 64) ws[OFF_MBS + t] = mb[t] + mb[64 + t] + mb[128 + t];
    }
}

// ---------------------------------------------------------------------------
// Kernel 2: att_m[b,h,m,n] = (sum_l X_l^T W X_l + a1[n] + a2[m] + 35*s)/2240
__global__ __launch_bounds__(256) void k_attm(const float* __restrict__ x,
                                              float* __restrict__ ws) {
    int b = blockIdx.x, h = blockIdx.y, t = threadIdx.x;
    __shared__ float sW[64 * 65];
    __shared__ float sX[64 * 24];
    __shared__ float sP[64 * 24];
    __shared__ float sQ[23 * 24];
    __shared__ float sA1[23], sA2[23];

    const float* xb = x + b * CNL;
    const float* Wg = ws + OFF_W + h * 4096;
    for (int i = t; i < 4096; i += 256) sW[(i >> 6) * 65 + (i & 63)] = Wg[i];
    for (int i = t; i < 552; i += 256) sQ[i] = 0.f;

    for (int i = t; i < 1472; i += 256) {
        int c = i / 23, n = i - c * 23;
        const float* p = xb + c * NNL + n * NL;
        float s = 0.f;
        for (int l = 0; l < NL; l++) s += p[l];
        sP[c * 24 + n] = s;
    }
    __syncthreads();
    if (t < 23) {
        float a = 0.f;
        const float* u = ws + OFF_U1 + h * 64;
        for (int c = 0; c < 64; c++) a += u[c] * sP[c * 24 + t];
        sA1[t] = a;
    } else if (t >= 32 && t < 55) {
        int n = t - 32;
        float a = 0.f;
        const float* u = ws + OFF_U2 + h * 64;
        for (int c = 0; c < 64; c++) a += u[c] * sP[c * 24 + n];
        sA2[n] = a;
    }

    int c2 = t & 63;
    int q  = t >> 6;
    int n0 = q * 6;
    int nv = (q == 3) ? 5 : 6;

    for (int l = 0; l < NL; l++) {
        __syncthreads();
        for (int i = t; i < 1472; i += 256) {
            int c = i / 23, n = i - c * 23;
            sX[c * 24 + n] = xb[c * NNL + n * NL + l];
        }
        if (t < 64) sX[t * 24 + 23] = 0.f;
        __syncthreads();
        float a0 = 0, a1 = 0, a2 = 0, a3 = 0, a4 = 0, a5 = 0;
        for (int c1 = 0; c1 < 64; c1++) {
            float w = sW[c2 * 65 + c1];
            const float* xr = &sX[c1 * 24 + n0];
            a0 += w * xr[0]; a1 += w * xr[1]; a2 += w * xr[2];
            a3 += w * xr[3]; a4 += w * xr[4]; a5 += w * xr[5];
        }
        float accs[6] = {a0, a1, a2, a3, a4, a5};
        for (int j = 0; j < nv; j++) sP[c2 * 24 + n0 + j] = accs[j];
        __syncthreads();
        for (int i = t; i < 529; i += 256) {
            int m = i / 23, n = i - m * 23;
            float a = 0.f;
            for (int c = 0; c < 64; c++) a += sX[c * 24 + m] * sP[c * 24 + n];
            sQ[m * 24 + n] += a;
        }
    }
    __syncthreads();
    float sh = ws[OFF_S + h];
    float* o = ws + OFF_ATTM + b * HF + h * NSQ;
    for (int i = t; i < 529; i += 256) {
        int m = i / 23, n = i - m * 23;
        o[i] = (sQ[m * 24 + n] + sA1[n] + sA2[m] + 35.f * sh) * (1.f / 2240.f);
    }
}

// ---------------------------------------------------------------------------
// Kernel 3: BN batch statistics per (h, feature).
__global__ __launch_bounds__(256) void k_bn(float* __restrict__ ws) {
    int f = blockIdx.x * 256 + threadIdx.x;
    if (f >= HF) return;
    const float* p = ws + OFF_ATTM + f;
    float s = 0.f, s2 = 0.f;
    for (int b = 0; b < NB; b++) {
        float v = p[b * HF];
        s += v; s2 += v * v;
    }
    float mean = s * (1.f / 256.f);
    float var  = s2 * (1.f / 256.f) - mean * mean;
    ws[OFF_MEAN + f] = mean;
    ws[OFF_RSTD + f] = rsqrtf(var + 1e-5f);
}

// ---------------------------------------------------------------------------
// Kernel 4: normalize, softmax over rows, A = A_ske + att + A_adp.
__global__ __launch_bounds__(256) void k_adp(const float* __restrict__ gamma,
                                             const float* __restrict__ beta,
                                             const float* __restrict__ att,
                                             const float* __restrict__ aske,
                                             float* __restrict__ ws) {
    int b = blockIdx.x, h = blockIdx.y, t = threadIdx.x;
    __shared__ float sv[529];
    const float* am   = ws + OFF_ATTM + b * HF + h * NSQ;
    const float* mean = ws + OFF_MEAN + h * NSQ;
    const float* rstd = ws + OFF_RSTD + h * NSQ;
    for (int i = t; i < 529; i += 256) {
        sv[i] = (am[i] - mean[i]) * rstd[i] * gamma[h * NSQ + i] + beta[h * NSQ + i];
    }
    __syncthreads();
    if (t < 23) {
        float mx = -1e30f;
        #pragma unroll
        for (int m = 0; m < 23; m++) mx = fmaxf(mx, sv[m * 23 + t]);
        float e[23];
        float sum = 0.f;
        #pragma unroll
        for (int m = 0; m < 23; m++) {
            float v = __expf(sv[m * 23 + t] - mx);
            e[m] = v; sum += v;
        }
        float inv = 1.f / sum;
        #pragma unroll
        for (int m = 0; m < 23; m++) sv[m * 23 + t] = e[m] * inv;
    }
    __syncthreads();
    float* o = ws + OFF_A + b * HF + h * NSQ;
    for (int i = t; i < 529; i += 256) {
        o[i] = sv[i] + aske[h * NSQ + i] + att[h * NSQ + i];
    }
}

// ---------------------------------------------------------------------------
// Kernel 5: graph conv, lane = o paradigm. No LDS, no barriers.
// Wave handles one (b, l); lane o holds mw[3][64] in regs; x and A arrive
// via wave-uniform scalar loads. y[b][m][l][o] written bf16 (coalesced).
__global__ __launch_bounds__(512, 2) void k_gcn(const float* __restrict__ x,
                                                const float* __restrict__ ws,
                                                bf16* __restrict__ ybuf,
                                                int pass) {
    const int ch = blockIdx.x;          // l-chunk of 8
    const int bb = blockIdx.y;          // 0..127 within pass
    const int b  = pass * 128 + bb;
    const int lane = threadIdx.x & 63;  // = o
    const int w = __builtin_amdgcn_readfirstlane((int)(threadIdx.x >> 6));
    const int l = ch * 8 + w;
    if (l >= NL) return;

    float mwreg[3][64];
    const float* mwt = ws + OFF_MWT;
    #pragma unroll
    for (int h = 0; h < 3; h++)
        #pragma unroll 16
        for (int c = 0; c < 64; c++)
            mwreg[h][c] = mwt[(h * 64 + c) * 64 + lane];

    float y[23];
    float mbs = ws[OFF_MBS + lane];
    #pragma unroll
    for (int m = 0; m < 23; m++) y[m] = mbs;

    const float* xn0 = x + b * CNL + l;       // + c*805 + n*35 (uniform)
    const float* A0 = ws + OFF_A + b * HF;    // + n*23 + m (uniform)
    const float* A1 = A0 + NSQ;
    const float* A2 = A1 + NSQ;

    for (int n = 0; n < NN; n++) {
        const float* xp = xn0 + n * NL;
        float z0 = 0.f, z1 = 0.f, z2 = 0.f;
        #pragma unroll 16
        for (int c = 0; c < 64; c++) {
            float xv = xp[c * NNL];           // wave-uniform -> s_load
            z0 += mwreg[0][c] * xv;
            z1 += mwreg[1][c] * xv;
            z2 += mwreg[2][c] * xv;
        }
        const float* a0 = A0 + n * NN;
        const float* a1 = A1 + n * NN;
        const float* a2 = A2 + n * NN;
        #pragma unroll
        for (int m = 0; m < 23; m++)
            y[m] += a0[m] * z0 + a1[m] * z1 + a2[m] * z2;
    }
    bf16* yp = ybuf + ((size_t)(bb * NN) * NL + l) * 64 + lane;
    #pragma unroll
    for (int m = 0; m < 23; m++)
        yp[(size_t)m * (NL * 64)] = __float2bfloat16(y[m]);
}

// ---------------------------------------------------------------------------
// Kernel 6: temporal FC. out[b,o,m,lp] = sum_l y[b,m,l,o]*W[l,lp] + bias[lp]
// lane = o (coalesced y loads); Wseq/bias via uniform scalar loads.
__global__ __launch_bounds__(512, 2) void k_fc(const float* __restrict__ wseq,
                                               const float* __restrict__ bias,
                                               const bf16* __restrict__ ybuf,
                                               float* __restrict__ out,
                                               int pass) {
    const int bb = blockIdx.x;
    const int b  = pass * 128 + bb;
    const int o  = threadIdx.x & 63;
    const int mg = __builtin_amdgcn_readfirstlane((int)(threadIdx.x >> 6)); // 0..7

    float acc[3][35];
    #pragma unroll
    for (int r = 0; r < 3; r++)
        #pragma unroll
        for (int lp = 0; lp < 35; lp++) acc[r][lp] = bias[lp];

    const bf16* yb = ybuf + o;
    for (int l = 0; l < NL; l++) {
        float y0 = __bfloat162float(yb[((size_t)(bb * NN + mg) * NL + l) * 64]);
        float y1 = __bfloat162float(yb[((size_t)(bb * NN + mg + 8) * NL + l) * 64]);
        float y2 = (mg < 7) ? __bfloat162float(yb[((size_t)(bb * NN + mg + 16) * NL + l) * 64]) : 0.f;
        const float* wr = wseq + l * 35;
        #pragma unroll
        for (int lp = 0; lp < 35; lp++) {
            float wv = wr[lp];                // uniform -> s_load
            acc[0][lp] += y0 * wv;
            acc[1][lp] += y1 * wv;
            acc[2][lp] += y2 * wv;
        }
    }
    #pragma unroll
    for (int r = 0; r < 3; r++) {
        int m = mg + 8 * r;
        if (m < 23) {
            float* op = out + ((size_t)(b * 64 + o) * 23 + m) * 35;
            #pragma unroll
            for (int lp = 0; lp < 35; lp++) op[lp] = acc[r][lp];
        }
    }
}

// ---------------------------------------------------------------------------
extern "C" void kernel_launch(void* const* d_in, const int* in_sizes, int n_in,
                              void* d_out, int out_size, void* d_ws, size_t ws_size,
                              hipStream_t stream) {
    const float* x    = (const float*)d_in[0];
    const float* cw1  = (const float*)d_in[1];
    const float* cb1  = (const float*)d_in[2];
    const float* cw2  = (const float*)d_in[3];
    const float* cb2  = (const float*)d_in[4];
    const float* gam  = (const float*)d_in[5];
    const float* bet  = (const float*)d_in[6];
    const float* mw   = (const float*)d_in[7];
    const float* mb   = (const float*)d_in[8];
    const float* att  = (const float*)d_in[9];
    const float* aske = (const float*)d_in[10];
    const float* wsq  = (const float*)d_in[11];
    const float* bias = (const float*)d_in[12];
    float* ws = (float*)d_ws;
    bf16* ybuf = (bf16*)(ws + OFF_Y);
    float* out = (float*)d_out;

    hipLaunchKernelGGL(k_prep, dim3(4),      dim3(256), 0, stream, cw1, cb1, cw2, cb2, mw, mb, ws);
    hipLaunchKernelGGL(k_attm, dim3(256, 3), dim3(256), 0, stream, x, ws);
    hipLaunchKernelGGL(k_bn,   dim3(7),      dim3(256), 0, stream, ws);
    hipLaunchKernelGGL(k_adp,  dim3(256, 3), dim3(256), 0, stream, gam, bet, att, aske, ws);
    hipLaunchKernelGGL(k_gcn,  dim3(5, 128), dim3(512), 0, stream, x, ws, ybuf, 0);
    hipLaunchKernelGGL(k_fc,   dim3(128),    dim3(512), 0, stream, wsq, bias, ybuf, out, 0);
    hipLaunchKernelGGL(k_gcn,  dim3(5, 128), dim3(512), 0, stream, x, ws, ybuf, 1);
    hipLaunchKernelGGL(k_fc,   dim3(128),    dim3(512), 0, stream, wsq, bias, ybuf, out, 1);
}

// Round 4
// 1005.424 us; speedup vs baseline: 2.3964x; 2.3955x over previous
//
#include <hip/hip_runtime.h>
#include <hip/hip_bf16.h>

typedef __hip_bfloat16 bf16;

// Problem constants
#define NB   256           // batch
#define NN   23            // nodes
#define NL   35            // seq len
#define NNL  805           // NN*NL
#define CNL  51520         // NC*NNL (per-batch x elements)
#define NSQ  529           // NN*NN
#define HF   1587          // NH*NSQ

// ws layout (float offsets)
#define OFF_W     0         // [3][64][64]
#define OFF_U1    12288
#define OFF_U2    12480
#define OFF_S     12672
#define OFF_ATTM  12800     // [256][1587]
#define OFF_MEAN  419072
#define OFF_RSTD  420672
#define OFF_A     422272    // [256][1587] -> ends 828544
#define OFF_MWT   828544    // mw transposed [3][64c][64o] -> 840832
#define OFF_MBS   840832    // mbsum[64] -> 840896 (pad 840960)
#define OFF_Y     840960    // bf16 y-buffer: per pass [128][23][35][64] = 13.2 MB
// total ws ~= 16.6 MB

// ---------------------------------------------------------------------------
// Kernel 1: fold projection weights; block 3 transposes mw and sums mb.
__global__ __launch_bounds__(256) void k_prep(const float* __restrict__ cw1,
                                              const float* __restrict__ cb1,
                                              const float* __restrict__ cw2,
                                              const float* __restrict__ cb2,
                                              const float* __restrict__ mw,
                                              const float* __restrict__ mb,
                                              float* __restrict__ ws) {
    int h = blockIdx.x, t = threadIdx.x;
    __shared__ float s1[4096], s2[4096];
    if (h < 3) {
        for (int i = t; i < 4096; i += 256) {
            s1[i] = cw1[h * 4096 + i];
            s2[i] = cw2[h * 4096 + i];
        }
        __syncthreads();
        for (int i = t; i < 4096; i += 256) {
            int c2 = i >> 6, c1 = i & 63;
            float acc = 0.f;
            for (int o = 0; o < 64; o++) acc += s2[o * 64 + c2] * s1[o * 64 + c1];
            ws[OFF_W + h * 4096 + i] = acc;
        }
        if (t < 64) {
            float a = 0.f, b2 = 0.f;
            for (int o = 0; o < 64; o++) {
                a  += cb2[h * 64 + o] * s1[o * 64 + t];
                b2 += cb1[h * 64 + o] * s2[o * 64 + t];
            }
            ws[OFF_U1 + h * 64 + t] = a;
            ws[OFF_U2 + h * 64 + t] = b2;
        }
        if (t == 0) {
            float a = 0.f;
            for (int o = 0; o < 64; o++) a += cb1[h * 64 + o] * cb2[h * 64 + o];
            ws[OFF_S + h] = a;
        }
    } else {
        // mwT[h][c][o] = mw[h][o][c]
        for (int i = t; i < 12288; i += 256) {
            int hh = i >> 12, rem = i & 4095, o = rem >> 6, c = rem & 63;
            ws[OFF_MWT + (hh * 64 + c) * 64 + o] = mw[i];
        }
        if (t < 64) ws[OFF_MBS + t] = mb[t] + mb[64 + t] + mb[128 + t];
    }
}

// ---------------------------------------------------------------------------
// Kernel 2: att_m[b,h,m,n] = (sum_l X_l^T W X_l + a1[n] + a2[m] + 35*s)/2240
__global__ __launch_bounds__(256) void k_attm(const float* __restrict__ x,
                                              float* __restrict__ ws) {
    int b = blockIdx.x, h = blockIdx.y, t = threadIdx.x;
    __shared__ float sW[64 * 65];
    __shared__ float sX[64 * 24];
    __shared__ float sP[64 * 24];
    __shared__ float sQ[23 * 24];
    __shared__ float sA1[23], sA2[23];

    const float* xb = x + b * CNL;
    const float* Wg = ws + OFF_W + h * 4096;
    for (int i = t; i < 4096; i += 256) sW[(i >> 6) * 65 + (i & 63)] = Wg[i];
    for (int i = t; i < 552; i += 256) sQ[i] = 0.f;

    for (int i = t; i < 1472; i += 256) {
        int c = i / 23, n = i - c * 23;
        const float* p = xb + c * NNL + n * NL;
        float s = 0.f;
        for (int l = 0; l < NL; l++) s += p[l];
        sP[c * 24 + n] = s;
    }
    __syncthreads();
    if (t < 23) {
        float a = 0.f;
        const float* u = ws + OFF_U1 + h * 64;
        for (int c = 0; c < 64; c++) a += u[c] * sP[c * 24 + t];
        sA1[t] = a;
    } else if (t >= 32 && t < 55) {
        int n = t - 32;
        float a = 0.f;
        const float* u = ws + OFF_U2 + h * 64;
        for (int c = 0; c < 64; c++) a += u[c] * sP[c * 24 + n];
        sA2[n] = a;
    }

    int c2 = t & 63;
    int q  = t >> 6;
    int n0 = q * 6;
    int nv = (q == 3) ? 5 : 6;

    for (int l = 0; l < NL; l++) {
        __syncthreads();
        for (int i = t; i < 1472; i += 256) {
            int c = i / 23, n = i - c * 23;
            sX[c * 24 + n] = xb[c * NNL + n * NL + l];
        }
        if (t < 64) sX[t * 24 + 23] = 0.f;
        __syncthreads();
        float a0 = 0, a1 = 0, a2 = 0, a3 = 0, a4 = 0, a5 = 0;
        for (int c1 = 0; c1 < 64; c1++) {
            float w = sW[c2 * 65 + c1];
            const float* xr = &sX[c1 * 24 + n0];
            a0 += w * xr[0]; a1 += w * xr[1]; a2 += w * xr[2];
            a3 += w * xr[3]; a4 += w * xr[4]; a5 += w * xr[5];
        }
        float accs[6] = {a0, a1, a2, a3, a4, a5};
        for (int j = 0; j < nv; j++) sP[c2 * 24 + n0 + j] = accs[j];
        __syncthreads();
        for (int i = t; i < 529; i += 256) {
            int m = i / 23, n = i - m * 23;
            float a = 0.f;
            for (int c = 0; c < 64; c++) a += sX[c * 24 + m] * sP[c * 24 + n];
            sQ[m * 24 + n] += a;
        }
    }
    __syncthreads();
    float sh = ws[OFF_S + h];
    float* o = ws + OFF_ATTM + b * HF + h * NSQ;
    for (int i = t; i < 529; i += 256) {
        int m = i / 23, n = i - m * 23;
        o[i] = (sQ[m * 24 + n] + sA1[n] + sA2[m] + 35.f * sh) * (1.f / 2240.f);
    }
}

// ---------------------------------------------------------------------------
// Kernel 3: BN batch statistics per (h, feature).
__global__ __launch_bounds__(256) void k_bn(float* __restrict__ ws) {
    int f = blockIdx.x * 256 + threadIdx.x;
    if (f >= HF) return;
    const float* p = ws + OFF_ATTM + f;
    float s = 0.f, s2 = 0.f;
    for (int b = 0; b < NB; b++) {
        float v = p[b * HF];
        s += v; s2 += v * v;
    }
    float mean = s * (1.f / 256.f);
    float var  = s2 * (1.f / 256.f) - mean * mean;
    ws[OFF_MEAN + f] = mean;
    ws[OFF_RSTD + f] = rsqrtf(var + 1e-5f);
}

// ---------------------------------------------------------------------------
// Kernel 4: normalize, softmax over rows, A = A_ske + att + A_adp.
__global__ __launch_bounds__(256) void k_adp(const float* __restrict__ gamma,
                                             const float* __restrict__ beta,
                                             const float* __restrict__ att,
                                             const float* __restrict__ aske,
                                             float* __restrict__ ws) {
    int b = blockIdx.x, h = blockIdx.y, t = threadIdx.x;
    __shared__ float sv[529];
    const float* am   = ws + OFF_ATTM + b * HF + h * NSQ;
    const float* mean = ws + OFF_MEAN + h * NSQ;
    const float* rstd = ws + OFF_RSTD + h * NSQ;
    for (int i = t; i < 529; i += 256) {
        sv[i] = (am[i] - mean[i]) * rstd[i] * gamma[h * NSQ + i] + beta[h * NSQ + i];
    }
    __syncthreads();
    if (t < 23) {
        float mx = -1e30f;
        #pragma unroll
        for (int m = 0; m < 23; m++) mx = fmaxf(mx, sv[m * 23 + t]);
        float e[23];
        float sum = 0.f;
        #pragma unroll
        for (int m = 0; m < 23; m++) {
            float v = __expf(sv[m * 23 + t] - mx);
            e[m] = v; sum += v;
        }
        float inv = 1.f / sum;
        #pragma unroll
        for (int m = 0; m < 23; m++) sv[m * 23 + t] = e[m] * inv;
    }
    __syncthreads();
    float* o = ws + OFF_A + b * HF + h * NSQ;
    for (int i = t; i < 529; i += 256) {
        o[i] = sv[i] + aske[h * NSQ + i] + att[h * NSQ + i];
    }
}

// ---------------------------------------------------------------------------
// Kernel 5: graph conv, lane = o paradigm. No LDS, no barriers.
// Wave handles one (b, l); lane o holds mw[3][64] in regs (FULLY UNROLLED so
// the array is register-resident; partial unroll demoted it to scratch in R3:
// VGPR=40, 2.34 GB scratch traffic). x and A arrive via wave-uniform scalar
// loads. y[b][m][l][o] written bf16 (coalesced).
__global__ __launch_bounds__(512, 2) void k_gcn(const float* __restrict__ x,
                                                const float* __restrict__ ws,
                                                bf16* __restrict__ ybuf,
                                                int pass) {
    const int ch = blockIdx.x;          // l-chunk of 8
    const int bb = blockIdx.y;          // 0..127 within pass
    const int b  = pass * 128 + bb;
    const int lane = threadIdx.x & 63;  // = o
    const int w = __builtin_amdgcn_readfirstlane((int)(threadIdx.x >> 6));
    const int l = ch * 8 + w;
    if (l >= NL) return;

    float mwreg[3][64];
    const float* mwt = ws + OFF_MWT;
    #pragma unroll
    for (int h = 0; h < 3; h++)
        #pragma unroll
        for (int c = 0; c < 64; c++)
            mwreg[h][c] = mwt[(h * 64 + c) * 64 + lane];

    float y[23];
    float mbs = ws[OFF_MBS + lane];
    #pragma unroll
    for (int m = 0; m < 23; m++) y[m] = mbs;

    const float* xn0 = x + b * CNL + l;       // + c*805 + n*35 (uniform)
    const float* A0 = ws + OFF_A + b * HF;    // + n*23 + m (uniform)
    const float* A1 = A0 + NSQ;
    const float* A2 = A1 + NSQ;

    for (int n = 0; n < NN; n++) {
        const float* xp = xn0 + n * NL;
        float z0 = 0.f, z1 = 0.f, z2 = 0.f;
        #pragma unroll
        for (int c = 0; c < 64; c++) {
            float xv = xp[c * NNL];           // wave-uniform -> s_load
            z0 += mwreg[0][c] * xv;
            z1 += mwreg[1][c] * xv;
            z2 += mwreg[2][c] * xv;
        }
        const float* a0 = A0 + n * NN;
        const float* a1 = A1 + n * NN;
        const float* a2 = A2 + n * NN;
        #pragma unroll
        for (int m = 0; m < 23; m++)
            y[m] += a0[m] * z0 + a1[m] * z1 + a2[m] * z2;
    }
    bf16* yp = ybuf + ((size_t)(bb * NN) * NL + l) * 64 + lane;
    #pragma unroll
    for (int m = 0; m < 23; m++)
        yp[(size_t)m * (NL * 64)] = __float2bfloat16(y[m]);
}

// ---------------------------------------------------------------------------
// Kernel 6: temporal FC. out[b,o,m,lp] = sum_l y[b,m,l,o]*W[l,lp] + bias[lp]
__global__ __launch_bounds__(512, 2) void k_fc(const float* __restrict__ wseq,
                                               const float* __restrict__ bias,
                                               const bf16* __restrict__ ybuf,
                                               float* __restrict__ out,
                                               int pass) {
    const int bb = blockIdx.x;
    const int b  = pass * 128 + bb;
    const int o  = threadIdx.x & 63;
    const int mg = __builtin_amdgcn_readfirstlane((int)(threadIdx.x >> 6)); // 0..7

    float acc[3][35];
    #pragma unroll
    for (int r = 0; r < 3; r++)
        #pragma unroll
        for (int lp = 0; lp < 35; lp++) acc[r][lp] = bias[lp];

    const bf16* yb = ybuf + o;
    for (int l = 0; l < NL; l++) {
        float y0 = __bfloat162float(yb[((size_t)(bb * NN + mg) * NL + l) * 64]);
        float y1 = __bfloat162float(yb[((size_t)(bb * NN + mg + 8) * NL + l) * 64]);
        float y2 = (mg < 7) ? __bfloat162float(yb[((size_t)(bb * NN + mg + 16) * NL + l) * 64]) : 0.f;
        const float* wr = wseq + l * 35;
        #pragma unroll
        for (int lp = 0; lp < 35; lp++) {
            float wv = wr[lp];                // uniform -> s_load
            acc[0][lp] += y0 * wv;
            acc[1][lp] += y1 * wv;
            acc[2][lp] += y2 * wv;
        }
    }
    #pragma unroll
    for (int r = 0; r < 3; r++) {
        int m = mg + 8 * r;
        if (m < 23) {
            float* op = out + ((size_t)(b * 64 + o) * 23 + m) * 35;
            #pragma unroll
            for (int lp = 0; lp < 35; lp++) op[lp] = acc[r][lp];
        }
    }
}

// ---------------------------------------------------------------------------
extern "C" void kernel_launch(void* const* d_in, const int* in_sizes, int n_in,
                              void* d_out, int out_size, void* d_ws, size_t ws_size,
                              hipStream_t stream) {
    const float* x    = (const float*)d_in[0];
    const float* cw1  = (const float*)d_in[1];
    const float* cb1  = (const float*)d_in[2];
    const float* cw2  = (const float*)d_in[3];
    const float* cb2  = (const float*)d_in[4];
    const float* gam  = (const float*)d_in[5];
    const float* bet  = (const float*)d_in[6];
    const float* mw   = (const float*)d_in[7];
    const float* mb   = (const float*)d_in[8];
    const float* att  = (const float*)d_in[9];
    const float* aske = (const float*)d_in[10];
    const float* wsq  = (const float*)d_in[11];
    const float* bias = (const float*)d_in[12];
    float* ws = (float*)d_ws;
    bf16* ybuf = (bf16*)(ws + OFF_Y);
    float* out = (float*)d_out;

    hipLaunchKernelGGL(k_prep, dim3(4),      dim3(256), 0, stream, cw1, cb1, cw2, cb2, mw, mb, ws);
    hipLaunchKernelGGL(k_attm, dim3(256, 3), dim3(256), 0, stream, x, ws);
    hipLaunchKernelGGL(k_bn,   dim3(7),      dim3(256), 0, stream, ws);
    hipLaunchKernelGGL(k_adp,  dim3(256, 3), dim3(256), 0, stream, gam, bet, att, aske, ws);
    hipLaunchKernelGGL(k_gcn,  dim3(5, 128), dim3(512), 0, stream, x, ws, ybuf, 0);
    hipLaunchKernelGGL(k_fc,   dim3(128),    dim3(512), 0, stream, wsq, bias, ybuf, out, 0);
    hipLaunchKernelGGL(k_gcn,  dim3(5, 128), dim3(512), 0, stream, x, ws, ybuf, 1);
    hipLaunchKernelGGL(k_fc,   dim3(128),    dim3(512), 0, stream, wsq, bias, ybuf, out, 1);
}

// Round 5
// 970.389 us; speedup vs baseline: 2.4829x; 1.0361x over previous
//
#include <hip/hip_runtime.h>
#include <hip/hip_bf16.h>

typedef __hip_bfloat16 bf16;

// Problem constants
#define NB   256           // batch
#define NN   23            // nodes
#define NL   35            // seq len
#define NNL  805           // NN*NL
#define CNL  51520         // NC*NNL (per-batch x elements)
#define NSQ  529           // NN*NN
#define HF   1587          // NH*NSQ
#define NCN  1472          // 64*23 (one X_l slice)

// ws layout (float offsets)
#define OFF_W     0         // [3][64][64]
#define OFF_U1    12288
#define OFF_U2    12480
#define OFF_S     12672
#define OFF_ATTM  12800     // [256][1587]
#define OFF_MEAN  419072
#define OFF_RSTD  420672
#define OFF_A     422272    // [256][1587] -> 828544
#define OFF_MWT   828544    // mwT [3][64c][64o] -> 840832
#define OFF_MBS   840832    // mbsum[64] -> pad 840960
#define OFF_XT    840960    // xt fp32 [256][35][1472] = 13,189,120 -> 14,030,080
#define OFF_Y     14030080  // bf16 ybuf per pass [128][23][35][64] = 13.2 MB
// total ~69.3 MB

// ---------------------------------------------------------------------------
// Kernel 0: transpose x[b][c][n][l] -> xt[b][l][c*23+n], fp32. Block per b.
__global__ __launch_bounds__(1024) void k_xt(const float* __restrict__ x,
                                             float* __restrict__ ws) {
    int b = blockIdx.x, t = threadIdx.x;
    __shared__ float sx[32 * 805];       // 103 KB: half the channels at a time
    const float* xb = x + b * CNL;
    float* xtb = ws + OFF_XT + b * CNL;  // [l][c*23+n]
    for (int ch = 0; ch < 2; ch++) {
        if (ch) __syncthreads();
        for (int i = t; i < 25760; i += 1024) sx[i] = xb[ch * 25760 + i];
        __syncthreads();
        // write: idx = l*736 + r, r = cc*23+n ; src sx[cc*805 + n*35 + l]
        for (int idx = t; idx < 25760; idx += 1024) {
            int l = idx / 736, r = idx - l * 736;
            int cc = r / 23, n = r - cc * 23;
            xtb[l * NCN + ch * 736 + r] = sx[cc * 805 + n * 35 + l];
        }
    }
}

// ---------------------------------------------------------------------------
// Kernel 1: fold projection weights; block 3 transposes mw and sums mb.
__global__ __launch_bounds__(256) void k_prep(const float* __restrict__ cw1,
                                              const float* __restrict__ cb1,
                                              const float* __restrict__ cw2,
                                              const float* __restrict__ cb2,
                                              const float* __restrict__ mw,
                                              const float* __restrict__ mb,
                                              float* __restrict__ ws) {
    int h = blockIdx.x, t = threadIdx.x;
    __shared__ float s1[4096], s2[4096];
    if (h < 3) {
        for (int i = t; i < 4096; i += 256) {
            s1[i] = cw1[h * 4096 + i];
            s2[i] = cw2[h * 4096 + i];
        }
        __syncthreads();
        for (int i = t; i < 4096; i += 256) {
            int c2 = i >> 6, c1 = i & 63;
            float acc = 0.f;
            for (int o = 0; o < 64; o++) acc += s2[o * 64 + c2] * s1[o * 64 + c1];
            ws[OFF_W + h * 4096 + i] = acc;
        }
        if (t < 64) {
            float a = 0.f, b2 = 0.f;
            for (int o = 0; o < 64; o++) {
                a  += cb2[h * 64 + o] * s1[o * 64 + t];
                b2 += cb1[h * 64 + o] * s2[o * 64 + t];
            }
            ws[OFF_U1 + h * 64 + t] = a;
            ws[OFF_U2 + h * 64 + t] = b2;
        }
        if (t == 0) {
            float a = 0.f;
            for (int o = 0; o < 64; o++) a += cb1[h * 64 + o] * cb2[h * 64 + o];
            ws[OFF_S + h] = a;
        }
    } else {
        for (int i = t; i < 12288; i += 256) {
            int hh = i >> 12, rem = i & 4095, o = rem >> 6, c = rem & 63;
            ws[OFF_MWT + (hh * 64 + c) * 64 + o] = mw[i];
        }
        if (t < 64) ws[OFF_MBS + t] = mb[t] + mb[64 + t] + mb[128 + t];
    }
}

// ---------------------------------------------------------------------------
// Kernel 2: att_m[b,h,m,n] = (sum_l X_l^T W X_l + a1[n] + a2[m] + 35*s)/2240
// Reads contiguous xt; stages 4 l-slices per barrier round.
__global__ __launch_bounds__(256) void k_attm(float* __restrict__ ws) {
    int b = blockIdx.x, h = blockIdx.y, t = threadIdx.x;
    __shared__ float sW[64 * 65];    // W rows padded 65 (conflict-free)
    __shared__ float sXc[4 * 1480];  // 4 X_l slices, stride 1480 (8 pad floats)
    __shared__ float sP[64 * 25];    // P[c2][n], stride 25 (24 gave 16-way write conflicts)
    __shared__ float sQ[23 * 24];    // attq accumulator
    __shared__ float sA1[23], sA2[23];

    const float* xtb = ws + OFF_XT + b * CNL;   // [l][i], i = c*23+n
    const float* Wg = ws + OFF_W + h * 4096;
    for (int i = t; i < 4096; i += 256) sW[(i >> 6) * 65 + (i & 63)] = Wg[i];
    for (int i = t; i < 552; i += 256) sQ[i] = 0.f;

    // xs[c][n] = sum_l xt[l][i]  (float4, coalesced) -> sP (stride 25)
    for (int r = 0; r < 2; r++) {
        int i4 = t + r * 256;
        if (i4 < 368) {
            float ax = 0, ay = 0, az = 0, aw = 0;
            for (int l = 0; l < NL; l++) {
                float4 v = *(const float4*)(xtb + l * NCN + i4 * 4);
                ax += v.x; ay += v.y; az += v.z; aw += v.w;
            }
            int i = i4 * 4;
            sP[((i    ) / 23) * 25 + (i    ) % 23] = ax;
            sP[((i + 1) / 23) * 25 + (i + 1) % 23] = ay;
            sP[((i + 2) / 23) * 25 + (i + 2) % 23] = az;
            sP[((i + 3) / 23) * 25 + (i + 3) % 23] = aw;
        }
    }
    __syncthreads();
    if (t < 23) {
        float a = 0.f;
        const float* u = ws + OFF_U1 + h * 64;
        for (int c = 0; c < 64; c++) a += u[c] * sP[c * 25 + t];
        sA1[t] = a;
    } else if (t >= 32 && t < 55) {
        int n = t - 32;
        float a = 0.f;
        const float* u = ws + OFF_U2 + h * 64;
        for (int c = 0; c < 64; c++) a += u[c] * sP[c * 25 + n];
        sA2[n] = a;
    }
    __syncthreads();   // sP free after this

    int c2 = t & 63;
    int q  = t >> 6;          // wave-uniform
    int n0 = q * 6;
    int nv = (q == 3) ? 5 : 6;

    for (int l0 = 0; l0 < NL; l0 += 4) {
        int Lc = (NL - l0 < 4) ? (NL - l0) : 4;
        // stage Lc slices (float4, coalesced; prev readers done at loop-end barrier)
        int cnt4 = Lc * 368;
        for (int idx4 = t; idx4 < cnt4; idx4 += 256) {
            int lp = idx4 / 368, i4 = idx4 - lp * 368;
            float4 v = *(const float4*)(xtb + (l0 + lp) * NCN + i4 * 4);
            *(float4*)(&sXc[lp * 1480 + i4 * 4]) = v;
        }
        __syncthreads();
        for (int lp = 0; lp < Lc; lp++) {
            const float* sX = &sXc[lp * 1480];
            // P[c2][n] = sum_c1 W[c2][c1]*X[c1][n], 6 n's per thread
            float a0 = 0, a1 = 0, a2 = 0, a3 = 0, a4 = 0, a5 = 0;
            for (int c1 = 0; c1 < 64; c1++) {
                float w = sW[c2 * 65 + c1];
                const float* xr = sX + c1 * 23 + n0;
                a0 += w * xr[0]; a1 += w * xr[1]; a2 += w * xr[2];
                a3 += w * xr[3]; a4 += w * xr[4]; a5 += w * xr[5];
            }
            float accs[6] = {a0, a1, a2, a3, a4, a5};
            for (int j = 0; j < nv; j++) sP[c2 * 25 + n0 + j] = accs[j];
            __syncthreads();
            // attq[m][n] += sum_c2 X[c2][m]*P[c2][n]
            for (int i = t; i < 529; i += 256) {
                int m = i / 23, n = i - m * 23;
                float a = 0.f;
                for (int c = 0; c < 64; c++) a += sX[c * 23 + m] * sP[c * 25 + n];
                sQ[m * 24 + n] += a;
            }
            __syncthreads();
        }
    }
    float sh = ws[OFF_S + h];
    float* o = ws + OFF_ATTM + b * HF + h * NSQ;
    for (int i = t; i < 529; i += 256) {
        int m = i / 23, n = i - m * 23;
        o[i] = (sQ[m * 24 + n] + sA1[n] + sA2[m] + 35.f * sh) * (1.f / 2240.f);
    }
}

// ---------------------------------------------------------------------------
// Kernel 3: BN batch statistics per (h, feature).
__global__ __launch_bounds__(256) void k_bn(float* __restrict__ ws) {
    int f = blockIdx.x * 256 + threadIdx.x;
    if (f >= HF) return;
    const float* p = ws + OFF_ATTM + f;
    float s = 0.f, s2 = 0.f;
    for (int b = 0; b < NB; b++) {
        float v = p[b * HF];
        s += v; s2 += v * v;
    }
    float mean = s * (1.f / 256.f);
    float var  = s2 * (1.f / 256.f) - mean * mean;
    ws[OFF_MEAN + f] = mean;
    ws[OFF_RSTD + f] = rsqrtf(var + 1e-5f);
}

// ---------------------------------------------------------------------------
// Kernel 4: normalize, softmax over rows, A = A_ske + att + A_adp.
__global__ __launch_bounds__(256) void k_adp(const float* __restrict__ gamma,
                                             const float* __restrict__ beta,
                                             const float* __restrict__ att,
                                             const float* __restrict__ aske,
                                             float* __restrict__ ws) {
    int b = blockIdx.x, h = blockIdx.y, t = threadIdx.x;
    __shared__ float sv[529];
    const float* am   = ws + OFF_ATTM + b * HF + h * NSQ;
    const float* mean = ws + OFF_MEAN + h * NSQ;
    const float* rstd = ws + OFF_RSTD + h * NSQ;
    for (int i = t; i < 529; i += 256) {
        sv[i] = (am[i] - mean[i]) * rstd[i] * gamma[h * NSQ + i] + beta[h * NSQ + i];
    }
    __syncthreads();
    if (t < 23) {
        float mx = -1e30f;
        #pragma unroll
        for (int m = 0; m < 23; m++) mx = fmaxf(mx, sv[m * 23 + t]);
        float e[23];
        float sum = 0.f;
        #pragma unroll
        for (int m = 0; m < 23; m++) {
            float v = __expf(sv[m * 23 + t] - mx);
            e[m] = v; sum += v;
        }
        float inv = 1.f / sum;
        #pragma unroll
        for (int m = 0; m < 23; m++) sv[m * 23 + t] = e[m] * inv;
    }
    __syncthreads();
    float* o = ws + OFF_A + b * HF + h * NSQ;
    for (int i = t; i < 529; i += 256) {
        o[i] = sv[i] + aske[h * NSQ + i] + att[h * NSQ + i];
    }
}

// ---------------------------------------------------------------------------
// Kernel 5: graph conv, lane = o. Wave = one (b,l). x rows are contiguous in
// xt -> uniform s_load_dwordx8 merges. h-loop ROLLED (forced) with per-h
// mwreg[64] fully unrolled so it stays register-resident (R3 lesson).
__global__ __launch_bounds__(256) void k_gcn(const float* __restrict__ ws,
                                             bf16* __restrict__ ybuf,
                                             int pass) {
    const int l  = blockIdx.x;          // 0..34
    const int by = blockIdx.y;          // 0..31
    const int lane = threadIdx.x & 63;  // = o
    const int w = __builtin_amdgcn_readfirstlane((int)(threadIdx.x >> 6));
    const int bb = by * 4 + w;          // 0..127 within pass
    const int b  = pass * 128 + bb;

    const float* xrow0 = ws + OFF_XT + ((size_t)b * NL + l) * NCN;
    const float* Ab    = ws + OFF_A + b * HF;
    const float* mwt   = ws + OFF_MWT;

    float y[23];
    float mbs = ws[OFF_MBS + lane];
    #pragma unroll
    for (int m = 0; m < 23; m++) y[m] = mbs;

    #pragma unroll 1
    for (int h = 0; h < 3; h++) {
        float mwreg[64];
        #pragma unroll
        for (int c = 0; c < 64; c++) mwreg[c] = mwt[(h * 64 + c) * 64 + lane];
        float z[23];
        #pragma unroll
        for (int n = 0; n < 23; n++) z[n] = 0.f;
        #pragma unroll
        for (int c = 0; c < 64; c++) {
            const float* xr = xrow0 + c * 23;   // uniform -> scalar loads
            #pragma unroll
            for (int n = 0; n < 23; n++) z[n] += mwreg[c] * xr[n];
        }
        const float* Ah = Ab + h * NSQ;
        #pragma unroll
        for (int n = 0; n < 23; n++) {
            float zn = z[n];
            #pragma unroll
            for (int m = 0; m < 23; m++) y[m] += Ah[n * 23 + m] * zn;
        }
    }
    bf16* yp = ybuf + ((size_t)(bb * NN) * NL + l) * 64 + lane;
    #pragma unroll
    for (int m = 0; m < 23; m++)
        yp[(size_t)m * (NL * 64)] = __float2bfloat16(y[m]);
}

// ---------------------------------------------------------------------------
// Kernel 6: temporal FC. out[b,o,m,lp] = sum_l y[b,m,l,o]*W[l,lp] + bias[lp]
__global__ __launch_bounds__(512, 2) void k_fc(const float* __restrict__ wseq,
                                               const float* __restrict__ bias,
                                               const bf16* __restrict__ ybuf,
                                               float* __restrict__ out,
                                               int pass) {
    const int bb = blockIdx.x;
    const int b  = pass * 128 + bb;
    const int o  = threadIdx.x & 63;
    const int mg = __builtin_amdgcn_readfirstlane((int)(threadIdx.x >> 6)); // 0..7

    float acc[3][35];
    #pragma unroll
    for (int r = 0; r < 3; r++)
        #pragma unroll
        for (int lp = 0; lp < 35; lp++) acc[r][lp] = bias[lp];

    const bf16* yb = ybuf + o;
    for (int l = 0; l < NL; l++) {
        float y0 = __bfloat162float(yb[((size_t)(bb * NN + mg) * NL + l) * 64]);
        float y1 = __bfloat162float(yb[((size_t)(bb * NN + mg + 8) * NL + l) * 64]);
        float y2 = (mg < 7) ? __bfloat162float(yb[((size_t)(bb * NN + mg + 16) * NL + l) * 64]) : 0.f;
        const float* wr = wseq + l * 35;
        #pragma unroll
        for (int lp = 0; lp < 35; lp++) {
            float wv = wr[lp];
            acc[0][lp] += y0 * wv;
            acc[1][lp] += y1 * wv;
            acc[2][lp] += y2 * wv;
        }
    }
    #pragma unroll
    for (int r = 0; r < 3; r++) {
        int m = mg + 8 * r;
        if (m < 23) {
            float* op = out + ((size_t)(b * 64 + o) * 23 + m) * 35;
            #pragma unroll
            for (int lp = 0; lp < 35; lp++) op[lp] = acc[r][lp];
        }
    }
}

// ---------------------------------------------------------------------------
extern "C" void kernel_launch(void* const* d_in, const int* in_sizes, int n_in,
                              void* d_out, int out_size, void* d_ws, size_t ws_size,
                              hipStream_t stream) {
    const float* x    = (const float*)d_in[0];
    const float* cw1  = (const float*)d_in[1];
    const float* cb1  = (const float*)d_in[2];
    const float* cw2  = (const float*)d_in[3];
    const float* cb2  = (const float*)d_in[4];
    const float* gam  = (const float*)d_in[5];
    const float* bet  = (const float*)d_in[6];
    const float* mw   = (const float*)d_in[7];
    const float* mb   = (const float*)d_in[8];
    const float* att  = (const float*)d_in[9];
    const float* aske = (const float*)d_in[10];
    const float* wsq  = (const float*)d_in[11];
    const float* bias = (const float*)d_in[12];
    float* ws = (float*)d_ws;
    bf16* ybuf = (bf16*)(ws + OFF_Y);
    float* out = (float*)d_out;

    hipLaunchKernelGGL(k_prep, dim3(4),       dim3(256),  0, stream, cw1, cb1, cw2, cb2, mw, mb, ws);
    hipLaunchKernelGGL(k_xt,   dim3(256),     dim3(1024), 0, stream, x, ws);
    hipLaunchKernelGGL(k_attm, dim3(256, 3),  dim3(256),  0, stream, ws);
    hipLaunchKernelGGL(k_bn,   dim3(7),       dim3(256),  0, stream, ws);
    hipLaunchKernelGGL(k_adp,  dim3(256, 3),  dim3(256),  0, stream, gam, bet, att, aske, ws);
    hipLaunchKernelGGL(k_gcn,  dim3(35, 32),  dim3(256),  0, stream, ws, ybuf, 0);
    hipLaunchKernelGGL(k_fc,   dim3(128),     dim3(512),  0, stream, wsq, bias, ybuf, out, 0);
    hipLaunchKernelGGL(k_gcn,  dim3(35, 32),  dim3(256),  0, stream, ws, ybuf, 1);
    hipLaunchKernelGGL(k_fc,   dim3(128),     dim3(512),  0, stream, wsq, bias, ybuf, out, 1);
}